// Round 5
// baseline (20.732 us; speedup 1.0000x reference)
//
#include <hip/hip_runtime.h>
#include <math.h>

namespace {

constexpr int kC = 16;    // channels
constexpr int kB = 32;    // rays
constexpr int kWavesPerBlock = 16;     // 1024 threads
constexpr int kSlabsPerWave  = 8;      // 16 * 8 = 128 slabs

// One block per ray. Wave w handles slabs {w + 16*j}. All reduction on-chip.
__global__ __launch_bounds__(1024)
void hpm_fused_kernel(const float* __restrict__ memory,
                      const float* __restrict__ ray_o,
                      const float* __restrict__ ray_d,
                      float* __restrict__ out)
{
    __shared__ float part[kWavesPerBlock][kC + 1];   // +1 pad: conflict-free column reads

    const int ray  = (int)blockIdx.x;                // 0..31
    const int wave = (int)(threadIdx.x >> 6);        // 0..15
    const int lane = (int)(threadIdx.x & 63);

    // Ray params: block-uniform -> scalar loads
    const float ox = ray_o[3 * ray + 0], oy = ray_o[3 * ray + 1], oz = ray_o[3 * ray + 2];
    const float dx = ray_d[3 * ray + 0], dy = ray_d[3 * ray + 1], dz = ray_d[3 * ray + 2];

    // Dominant axis a0 (|d_a0| >= 1/sqrt(3)); permuted frame (a0, a1, a2)
    const float adx = fabsf(dx), ady = fabsf(dy), adz = fabsf(dz);
    int a0;
    if (adx >= ady && adx >= adz) a0 = 0; else if (ady >= adz) a0 = 1; else a0 = 2;
    const float o0 = (a0 == 0) ? ox : ((a0 == 1) ? oy : oz);
    const float d0 = (a0 == 0) ? dx : ((a0 == 1) ? dy : dz);
    const float o1 = (a0 == 0) ? oy : ox;   // a1 = (a0==0) ? y : x
    const float d1 = (a0 == 0) ? dy : dx;
    const float o2 = (a0 == 2) ? oy : oz;   // a2 = (a0==2) ? y : z
    const float d2 = (a0 == 2) ? dy : dz;
    const int st0 = (a0 == 0) ? 16384 : ((a0 == 1) ? 128 : 1);
    const int st1 = (a0 == 0) ? 128 : 16384;
    const int st2 = (a0 == 2) ? 128 : 1;
    const float inv_d0 = 1.0f / d0;          // |d0| >= 1/sqrt(3), never 0

    const float4* __restrict__ mem4 = reinterpret_cast<const float4*>(memory);

    float a[kC];
    #pragma unroll
    for (int i = 0; i < kC; ++i) a[i] = 0.0f;
    bool anyhit = false;

    #pragma unroll
    for (int j = 0; j < kSlabsPerWave; ++j) {
        const int slab = wave + kWavesPerBlock * j;    // 0..127
        const float sa  = (float)slab;
        const float t_s = (sa - o0) * inv_d0;
        const float c1  = fmaf(t_s, d1, o1);
        const float c2  = fmaf(t_s, d2, o2);

        // Conservative slab cull. Note the tube extends over the FULL backward
        // half-line (t<0 has no decay), so only forward t is bounded (t<32 from
        // exp(-t/2) cutoff; +6.4 slack for window extent -> 38.5).
        const bool slab_ok = (fmaxf(t_s, 0.0f) < 38.5f) &&
                             (c1 > -5.5f) && (c1 < 132.5f) &&
                             (c2 > -5.5f) && (c2 < 132.5f);
        if (!slab_ok) continue;

        const int r1  = (int)rintf(c1);
        const int r2i = (int)rintf(c2);
        #pragma unroll
        for (int cc = 0; cc < 2; ++cc) {
            const int q = lane + cc * 64;          // candidate id in 11x11 window
            if (q < 121) {
                const int y = r1  + (q / 11) - 5;  // axis-a1 coordinate
                const int z = r2i + (q % 11) - 5;  // axis-a2 coordinate
                if ((unsigned)y < 128u && (unsigned)z < 128u) {
                    const float e0 = sa - o0;
                    const float e1 = (float)y - o1;
                    const float e2 = (float)z - o2;
                    const float t  = fmaf(e0, d0, fmaf(e1, d1, e2 * d2));
                    const float g0 = fmaf(-t, d0, e0);
                    const float g1 = fmaf(-t, d1, e1);
                    const float g2 = fmaf(-t, d2, e2);
                    const float rr = fmaf(g0, g0, fmaf(g1, g1, g2 * g2));
                    const float arg = fmaf(-2.0f, rr, -0.5f * fmaxf(t, 0.0f));
                    if (arg > -16.0f) {            // e^-16 tail negligible vs 1e-2 thr
                        const float k = __expf(arg);
                        const int idx = slab * st0 + y * st1 + z * st2;
                        const float4 m0 = mem4[idx * 4 + 0];
                        const float4 m1 = mem4[idx * 4 + 1];
                        const float4 m2 = mem4[idx * 4 + 2];
                        const float4 m3 = mem4[idx * 4 + 3];
                        a[ 0] = fmaf(k, m0.x, a[ 0]); a[ 1] = fmaf(k, m0.y, a[ 1]);
                        a[ 2] = fmaf(k, m0.z, a[ 2]); a[ 3] = fmaf(k, m0.w, a[ 3]);
                        a[ 4] = fmaf(k, m1.x, a[ 4]); a[ 5] = fmaf(k, m1.y, a[ 5]);
                        a[ 6] = fmaf(k, m1.z, a[ 6]); a[ 7] = fmaf(k, m1.w, a[ 7]);
                        a[ 8] = fmaf(k, m2.x, a[ 8]); a[ 9] = fmaf(k, m2.y, a[ 9]);
                        a[10] = fmaf(k, m2.z, a[10]); a[11] = fmaf(k, m2.w, a[11]);
                        a[12] = fmaf(k, m3.x, a[12]); a[13] = fmaf(k, m3.y, a[13]);
                        a[14] = fmaf(k, m3.z, a[14]); a[15] = fmaf(k, m3.w, a[15]);
                        anyhit = true;
                    }
                }
            }
        }
    }

    // Per-wave butterfly (skipped entirely by all-miss waves), then LDS partial.
    if (__ballot(anyhit) != 0ull) {
        #pragma unroll
        for (int c = 0; c < kC; ++c) {
            float v = a[c];
            v += __shfl_xor(v,  1); v += __shfl_xor(v,  2);
            v += __shfl_xor(v,  4); v += __shfl_xor(v,  8);
            v += __shfl_xor(v, 16); v += __shfl_xor(v, 32);
            a[c] = v;
        }
    }
    if (lane == 0) {
        #pragma unroll
        for (int c = 0; c < kC; ++c) part[wave][c] = a[c];
    }
    __syncthreads();

    // Block reduce: 16 threads, one channel each, sum 16 wave partials.
    if (threadIdx.x < kC) {
        const int c = (int)threadIdx.x;
        float s = 0.0f;
        #pragma unroll
        for (int w = 0; w < kWavesPerBlock; ++w) s += part[w][c];
        out[ray * kC + c] = s;
    }
}

} // namespace

extern "C" void kernel_launch(void* const* d_in, const int* in_sizes, int n_in,
                              void* d_out, int out_size, void* d_ws, size_t ws_size,
                              hipStream_t stream) {
    const float* memory = (const float*)d_in[0];
    // d_in[1] = grid : unused, coordinates are implied by the linear index
    const float* ray_o  = (const float*)d_in[2];
    const float* ray_d  = (const float*)d_in[3];
    float* out = (float*)d_out;

    hpm_fused_kernel<<<kB, 1024, 0, stream>>>(memory, ray_o, ray_d, out);
}

// Round 6
// 16.246 us; speedup vs baseline: 1.2761x; 1.2761x over previous
//
#include <hip/hip_runtime.h>
#include <math.h>

namespace {

constexpr int kC = 16;    // channels
constexpr int kB = 32;    // rays
constexpr int kSlabs = 128;
// Stage 1: one wave per (ray, slab, half-window): 32*128*2 = 8192 waves.
constexpr int kS1Blocks = kB * kSlabs * 2 / 4;   // 4 waves/block -> 2048 blocks

// Stage 1: wave computes a half-window (<=64 candidates, ONE load batch) of
// one (ray, slab); block reduces its 4 wave partials; one 64B ws write.
__global__ __launch_bounds__(256)
void hpm_stage1(const float* __restrict__ memory,
                const float* __restrict__ ray_o,
                const float* __restrict__ ray_d,
                float* __restrict__ ws)
{
    __shared__ float part[4][kC];

    const int b    = (int)blockIdx.x;            // 0..2047
    const int ray  = b >> 6;                     // 0..31
    const int sg   = b & 63;                     // slab pair id
    const int w    = (int)(threadIdx.x >> 6);    // 0..3
    const int lane = (int)(threadIdx.x & 63);
    const int slab = sg * 2 + (w >> 1);          // 0..127
    const int half = w & 1;                      // window half

    // Per-thread constant candidate offset in the 11x11 window
    const int q   = half * 64 + lane;            // 0..127
    const bool qv = (q < 121);
    const int off1 = q / 11 - 5;                 // axis-a1 offset
    const int off2 = q % 11 - 5;                 // axis-a2 offset

    // Ray params: block-uniform -> scalar loads
    const float ox = ray_o[3 * ray + 0], oy = ray_o[3 * ray + 1], oz = ray_o[3 * ray + 2];
    const float dx = ray_d[3 * ray + 0], dy = ray_d[3 * ray + 1], dz = ray_d[3 * ray + 2];

    // Dominant axis a0 (|d_a0| >= 1/sqrt(3)); permuted frame (a0, a1, a2)
    const float adx = fabsf(dx), ady = fabsf(dy), adz = fabsf(dz);
    int a0;
    if (adx >= ady && adx >= adz) a0 = 0; else if (ady >= adz) a0 = 1; else a0 = 2;
    const float o0 = (a0 == 0) ? ox : ((a0 == 1) ? oy : oz);
    const float d0 = (a0 == 0) ? dx : ((a0 == 1) ? dy : dz);
    const float o1 = (a0 == 0) ? oy : ox;   // a1 = (a0==0) ? y : x
    const float d1 = (a0 == 0) ? dy : dx;
    const float o2 = (a0 == 2) ? oy : oz;   // a2 = (a0==2) ? y : z
    const float d2 = (a0 == 2) ? dy : dz;
    const int st0 = (a0 == 0) ? 16384 : ((a0 == 1) ? 128 : 1);
    const int st1 = (a0 == 0) ? 128 : 16384;
    const int st2 = (a0 == 2) ? 128 : 1;

    // Slab-plane / line intersection
    const float sa  = (float)slab;
    const float t_s = (sa - o0) / d0;            // |d0| >= 1/sqrt(3)
    const float c1  = fmaf(t_s, d1, o1);
    const float c2  = fmaf(t_s, d2, o2);

    // Conservative slab cull: backward half-line has no decay (t<0), forward
    // decay kills t_s > 38.5; in-plane footprint +-5.41 around the center.
    const bool slab_ok = (fmaxf(t_s, 0.0f) < 38.5f) &&
                         (c1 > -5.5f) && (c1 < 132.5f) &&
                         (c2 > -5.5f) && (c2 < 132.5f);

    float a[kC];
    #pragma unroll
    for (int i = 0; i < kC; ++i) a[i] = 0.0f;
    bool hit = false;

    if (slab_ok && qv) {
        const int y = (int)rintf(c1) + off1;     // axis-a1 coordinate
        const int z = (int)rintf(c2) + off2;     // axis-a2 coordinate
        if ((unsigned)y < 128u && (unsigned)z < 128u) {
            const float e0 = sa - o0;
            const float e1 = (float)y - o1;
            const float e2 = (float)z - o2;
            const float t  = fmaf(e0, d0, fmaf(e1, d1, e2 * d2));
            const float g0 = fmaf(-t, d0, e0);
            const float g1 = fmaf(-t, d1, e1);
            const float g2 = fmaf(-t, d2, e2);
            const float rr = fmaf(g0, g0, fmaf(g1, g1, g2 * g2));
            const float arg = fmaf(-2.0f, rr, -0.5f * fmaxf(t, 0.0f));
            if (arg > -16.0f) {                  // e^-16 tail negligible
                const float k = __expf(arg);
                const int idx = slab * st0 + y * st1 + z * st2;
                const float4* __restrict__ mem4 = reinterpret_cast<const float4*>(memory);
                const float4 m0 = mem4[idx * 4 + 0];
                const float4 m1 = mem4[idx * 4 + 1];
                const float4 m2 = mem4[idx * 4 + 2];
                const float4 m3 = mem4[idx * 4 + 3];
                a[ 0] = k * m0.x; a[ 1] = k * m0.y; a[ 2] = k * m0.z; a[ 3] = k * m0.w;
                a[ 4] = k * m1.x; a[ 5] = k * m1.y; a[ 6] = k * m1.z; a[ 7] = k * m1.w;
                a[ 8] = k * m2.x; a[ 9] = k * m2.y; a[10] = k * m2.z; a[11] = k * m2.w;
                a[12] = k * m3.x; a[13] = k * m3.y; a[14] = k * m3.z; a[15] = k * m3.w;
                hit = true;
            }
        }
    }

    // Wave butterfly (skipped by all-miss waves), every wave writes its partial.
    if (__ballot(hit) != 0ull) {
        #pragma unroll
        for (int c = 0; c < kC; ++c) {
            float v = a[c];
            v += __shfl_xor(v,  1); v += __shfl_xor(v,  2);
            v += __shfl_xor(v,  4); v += __shfl_xor(v,  8);
            v += __shfl_xor(v, 16); v += __shfl_xor(v, 32);
            a[c] = v;
        }
    }
    if (lane == 0) {
        #pragma unroll
        for (int c = 0; c < kC; ++c) part[w][c] = a[c];
    }
    __syncthreads();

    // Block reduce 4 partials -> one coalesced 64B store into the block's slot.
    if (threadIdx.x < kC) {
        const int c = (int)threadIdx.x;
        ws[b * kC + c] = (part[0][c] + part[1][c]) + (part[2][c] + part[3][c]);
    }
}

// Stage 2: out[ray*16+c] = sum over the ray's 64 block partials.
__global__ __launch_bounds__(256)
void hpm_stage2(const float* __restrict__ ws, float* __restrict__ out)
{
    __shared__ float red[16][kC + 1];
    const int ray = (int)blockIdx.x;             // 0..31
    const int t = (int)threadIdx.x;
    const int g = t >> 4;                        // 0..15 (group of 4 partials)
    const int c = t & 15;
    const float* __restrict__ p = ws + (ray * 64 + g * 4) * kC + c;
    const float s = (p[0] + p[kC]) + (p[2 * kC] + p[3 * kC]);
    red[g][c] = s;
    __syncthreads();
    if (t < kC) {
        float s2 = 0.0f;
        #pragma unroll
        for (int w = 0; w < 16; ++w) s2 += red[w][t];
        out[ray * kC + t] = s2;
    }
}

} // namespace

extern "C" void kernel_launch(void* const* d_in, const int* in_sizes, int n_in,
                              void* d_out, int out_size, void* d_ws, size_t ws_size,
                              hipStream_t stream) {
    const float* memory = (const float*)d_in[0];
    // d_in[1] = grid : unused, coordinates are implied by the linear index
    const float* ray_o  = (const float*)d_in[2];
    const float* ray_d  = (const float*)d_in[3];
    float* out = (float*)d_out;
    float* ws  = (float*)d_ws;    // 2048 * 16 * 4B = 128 KB scratch

    hpm_stage1<<<kS1Blocks, 256, 0, stream>>>(memory, ray_o, ray_d, ws);
    hpm_stage2<<<kB, 256, 0, stream>>>(ws, out);
}

// Round 7
// 13.243 us; speedup vs baseline: 1.5655x; 1.2268x over previous
//
#include <hip/hip_runtime.h>
#include <math.h>

namespace {

constexpr int kC = 16;    // channels
constexpr int kB = 32;    // rays
constexpr int kSlabs = 128;
// Stage 1: one wave per (ray, slab): 4096 waves, 4 waves/block -> 1024 blocks.
constexpr int kS1Blocks = kB * kSlabs / 4;
constexpr int kSlotsPerRay = kSlabs / 4;         // 32 ws slots per ray

// Stage 1: wave tests the full 11x11 window of one (ray, slab) in two
// predicated batches; block reduces its 4 wave partials; one 64B ws write.
__global__ __launch_bounds__(256)
void hpm_stage1(const float* __restrict__ memory,
                const float* __restrict__ ray_o,
                const float* __restrict__ ray_d,
                float* __restrict__ ws)
{
    __shared__ float part[4][kC];

    const int b    = (int)blockIdx.x;            // 0..1023
    const int ray  = b >> 5;                     // 0..31
    const int sg   = b & 31;                     // slab group of 4
    const int w    = (int)(threadIdx.x >> 6);    // 0..3
    const int lane = (int)(threadIdx.x & 63);
    const int slab = sg * 4 + w;                 // 0..127

    // Ray params: block-uniform -> scalar loads
    const float ox = ray_o[3 * ray + 0], oy = ray_o[3 * ray + 1], oz = ray_o[3 * ray + 2];
    const float dx = ray_d[3 * ray + 0], dy = ray_d[3 * ray + 1], dz = ray_d[3 * ray + 2];

    // Dominant axis a0 (|d_a0| >= 1/sqrt(3)); permuted frame (a0, a1, a2)
    const float adx = fabsf(dx), ady = fabsf(dy), adz = fabsf(dz);
    int a0;
    if (adx >= ady && adx >= adz) a0 = 0; else if (ady >= adz) a0 = 1; else a0 = 2;
    const float o0 = (a0 == 0) ? ox : ((a0 == 1) ? oy : oz);
    const float d0 = (a0 == 0) ? dx : ((a0 == 1) ? dy : dz);
    const float o1 = (a0 == 0) ? oy : ox;   // a1 = (a0==0) ? y : x
    const float d1 = (a0 == 0) ? dy : dx;
    const float o2 = (a0 == 2) ? oy : oz;   // a2 = (a0==2) ? y : z
    const float d2 = (a0 == 2) ? dy : dz;
    const int st0 = (a0 == 0) ? 16384 : ((a0 == 1) ? 128 : 1);
    const int st1 = (a0 == 0) ? 128 : 16384;
    const int st2 = (a0 == 2) ? 128 : 1;

    // Slab-plane / line intersection
    const float sa  = (float)slab;
    const float t_s = (sa - o0) / d0;            // |d0| >= 1/sqrt(3)
    const float c1  = fmaf(t_s, d1, o1);
    const float c2  = fmaf(t_s, d2, o2);

    // Conservative slab cull: backward half-line has no decay (t<0); forward
    // decay kills t_s > 38.5; in-plane footprint +-5.41 around the center.
    const bool slab_ok = (fmaxf(t_s, 0.0f) < 38.5f) &&
                         (c1 > -5.5f) && (c1 < 132.5f) &&
                         (c2 > -5.5f) && (c2 < 132.5f);

    float a[kC];
    #pragma unroll
    for (int i = 0; i < kC; ++i) a[i] = 0.0f;
    bool hit = false;

    if (slab_ok) {
        const int r1  = (int)rintf(c1);
        const int r2i = (int)rintf(c2);
        const float4* __restrict__ mem4 = reinterpret_cast<const float4*>(memory);
        #pragma unroll
        for (int cc = 0; cc < 2; ++cc) {
            const int q = lane + cc * 64;          // candidate id in 11x11 window
            if (q < 121) {
                const int y = r1  + (q / 11) - 5;  // axis-a1 coordinate
                const int z = r2i + (q % 11) - 5;  // axis-a2 coordinate
                if ((unsigned)y < 128u && (unsigned)z < 128u) {
                    const float e0 = sa - o0;
                    const float e1 = (float)y - o1;
                    const float e2 = (float)z - o2;
                    const float t  = fmaf(e0, d0, fmaf(e1, d1, e2 * d2));
                    const float g0 = fmaf(-t, d0, e0);
                    const float g1 = fmaf(-t, d1, e1);
                    const float g2 = fmaf(-t, d2, e2);
                    const float rr = fmaf(g0, g0, fmaf(g1, g1, g2 * g2));
                    const float arg = fmaf(-2.0f, rr, -0.5f * fmaxf(t, 0.0f));
                    if (arg > -16.0f) {            // e^-16 tail negligible
                        const float k = __expf(arg);
                        const int idx = slab * st0 + y * st1 + z * st2;
                        const float4 m0 = mem4[idx * 4 + 0];
                        const float4 m1 = mem4[idx * 4 + 1];
                        const float4 m2 = mem4[idx * 4 + 2];
                        const float4 m3 = mem4[idx * 4 + 3];
                        a[ 0] = fmaf(k, m0.x, a[ 0]); a[ 1] = fmaf(k, m0.y, a[ 1]);
                        a[ 2] = fmaf(k, m0.z, a[ 2]); a[ 3] = fmaf(k, m0.w, a[ 3]);
                        a[ 4] = fmaf(k, m1.x, a[ 4]); a[ 5] = fmaf(k, m1.y, a[ 5]);
                        a[ 6] = fmaf(k, m1.z, a[ 6]); a[ 7] = fmaf(k, m1.w, a[ 7]);
                        a[ 8] = fmaf(k, m2.x, a[ 8]); a[ 9] = fmaf(k, m2.y, a[ 9]);
                        a[10] = fmaf(k, m2.z, a[10]); a[11] = fmaf(k, m2.w, a[11]);
                        a[12] = fmaf(k, m3.x, a[12]); a[13] = fmaf(k, m3.y, a[13]);
                        a[14] = fmaf(k, m3.z, a[14]); a[15] = fmaf(k, m3.w, a[15]);
                        hit = true;
                    }
                }
            }
        }
    }

    // Wave butterfly (skipped entirely by all-miss waves).
    if (__ballot(hit) != 0ull) {
        #pragma unroll
        for (int c = 0; c < kC; ++c) {
            float v = a[c];
            v += __shfl_xor(v,  1); v += __shfl_xor(v,  2);
            v += __shfl_xor(v,  4); v += __shfl_xor(v,  8);
            v += __shfl_xor(v, 16); v += __shfl_xor(v, 32);
            a[c] = v;
        }
    }
    if (lane == 0) {
        #pragma unroll
        for (int c = 0; c < kC; ++c) part[w][c] = a[c];
    }
    __syncthreads();

    // Block reduce 4 partials -> one coalesced 64B store into the block's slot.
    if (threadIdx.x < kC) {
        const int c = (int)threadIdx.x;
        ws[b * kC + c] = (part[0][c] + part[1][c]) + (part[2][c] + part[3][c]);
    }
}

// Stage 2: out[ray*16+c] = sum over the ray's 32 block partials.
__global__ __launch_bounds__(256)
void hpm_stage2(const float* __restrict__ ws, float* __restrict__ out)
{
    __shared__ float red[16][kC + 1];
    const int ray = (int)blockIdx.x;             // 0..31
    const int t = (int)threadIdx.x;
    const int g = t >> 4;                        // 0..15 (group of 2 partials)
    const int c = t & 15;
    const float* __restrict__ p = ws + (ray * kSlotsPerRay + g * 2) * kC + c;
    red[g][c] = p[0] + p[kC];
    __syncthreads();
    if (t < kC) {
        float s2 = 0.0f;
        #pragma unroll
        for (int w = 0; w < 16; ++w) s2 += red[w][t];
        out[ray * kC + t] = s2;
    }
}

} // namespace

extern "C" void kernel_launch(void* const* d_in, const int* in_sizes, int n_in,
                              void* d_out, int out_size, void* d_ws, size_t ws_size,
                              hipStream_t stream) {
    const float* memory = (const float*)d_in[0];
    // d_in[1] = grid : unused, coordinates are implied by the linear index
    const float* ray_o  = (const float*)d_in[2];
    const float* ray_d  = (const float*)d_in[3];
    float* out = (float*)d_out;
    float* ws  = (float*)d_ws;    // 1024 * 16 * 4B = 64 KB scratch

    hpm_stage1<<<kS1Blocks, 256, 0, stream>>>(memory, ray_o, ray_d, ws);
    hpm_stage2<<<kB, 256, 0, stream>>>(ws, out);
}